// Round 6
// baseline (131.969 us; speedup 1.0000x reference)
//
#include <hip/hip_runtime.h>
#include <math.h>

// Problem constants (fixed by setup_inputs): N_ref=128, N_src=128, D=256.
#define NREF 128
#define NSRC 128
#define DIM  256
#define EPS  1e-5f

// ---------------------------------------------------------------------------
// K1 (129 blocks x 512):
//  blocks 0..127: feat row i = ref_feats[i].src_feats[j] (all j), row argmax,
//    and per-COLUMN argmax via atomicMax on packed u64:
//    (orderkey(value) << 32) | (127 - i)  -> lexicographic max == (max value,
//    min i) == jnp first-occurrence argmax. Decode is bit-lossless.
//  block 128: point pipeline -> pts_ws.
// ---------------------------------------------------------------------------
__global__ __launch_bounds__(512) void feat_kernel(
    const float* __restrict__ ref_feats,
    const float* __restrict__ src_feats,
    const float* __restrict__ points_c,
    const float* __restrict__ trans,
    float* __restrict__ feat_mat,
    float* __restrict__ rowF, int* __restrict__ rowFi,
    unsigned long long* __restrict__ colmax,
    float* __restrict__ pts_ws)     // [px 256 | py 256 | pz 256 | nsq 256]
{
    __shared__ __align__(16) float refrow[DIM];
    __shared__ float wmv[8];  __shared__ int wmi[8];
    __shared__ float wred[16], red[4];

    const int t = threadIdx.x;
    const int w = t >> 6, l = t & 63;

    if (blockIdx.x == 128) {
        // ---- points block (threads 0..255 active) ----
        float x = 0.f, y = 0.f, z = 0.f;
        if (t < 256) {
            x = points_c[3 * t + 0];
            y = points_c[3 * t + 1];
            z = points_c[3 * t + 2];
            if (t >= NREF) {
                float nx = trans[0] * x + trans[1] * y + trans[2]  * z + trans[3];
                float ny = trans[4] * x + trans[5] * y + trans[6]  * z + trans[7];
                float nz = trans[8] * x + trans[9] * y + trans[10] * z + trans[11];
                x = nx; y = ny; z = nz;
            }
            float sx = x, sy = y, sz = z;
            for (int off = 32; off >= 1; off >>= 1) {
                sx += __shfl_down(sx, off);
                sy += __shfl_down(sy, off);
                sz += __shfl_down(sz, off);
            }
            if (l == 0) { wred[w] = sx; wred[4 + w] = sy; wred[8 + w] = sz; }
        }
        __syncthreads();
        if (t == 0) {
            red[0] = (wred[0] + wred[1] + wred[2] + wred[3]) * (1.0f / 256.0f);
            red[1] = (wred[4] + wred[5] + wred[6] + wred[7]) * (1.0f / 256.0f);
            red[2] = (wred[8] + wred[9] + wred[10] + wred[11]) * (1.0f / 256.0f);
        }
        __syncthreads();
        if (t < 256) {
            x -= red[0]; y -= red[1]; z -= red[2];
            float n = x * x + y * y + z * z;
            float mx = n;
            for (int off = 32; off >= 1; off >>= 1)
                mx = fmaxf(mx, __shfl_down(mx, off));
            if (l == 0) wred[w] = mx;
        }
        __syncthreads();
        if (t == 0)
            red[3] = 1.0f / sqrtf(fmaxf(fmaxf(wred[0], wred[1]), fmaxf(wred[2], wred[3])));
        __syncthreads();
        if (t < 256) {
            const float inv = red[3];
            x *= inv; y *= inv; z *= inv;
            pts_ws[t]       = x;
            pts_ws[256 + t] = y;
            pts_ws[512 + t] = z;
            pts_ws[768 + t] = x * x + y * y + z * z;
        }
        return;
    }

    // ---- feat row block ----
    const int i = blockIdx.x;
    if (t < 64) ((float4*)refrow)[t] = ((const float4*)(ref_feats + i * DIM))[t];
    __syncthreads();

    const float4 r = ((const float4*)refrow)[l];

    // 16 dwordx4 loads in flight (fully unrolled), then xor-butterfly reduce
    // (same summation tree as the lane-0 down-tree -> bitwise-identical sums).
    float dot[16];
#pragma unroll
    for (int m = 0; m < 16; ++m) {
        const float4 a = ((const float4*)(src_feats + (w * 16 + m) * DIM))[l];
        dot[m] = a.x * r.x + a.y * r.y + a.z * r.z + a.w * r.w;
    }
#pragma unroll
    for (int m = 0; m < 16; ++m) {
        float s = dot[m];
        s += __shfl_xor(s, 32);
        s += __shfl_xor(s, 16);
        s += __shfl_xor(s, 8);
        s += __shfl_xor(s, 4);
        s += __shfl_xor(s, 2);
        s += __shfl_xor(s, 1);
        dot[m] = s;
    }

    if (l == 0) {
        const int j0 = w * 16;
        // coalesced row store (4 x dwordx4)
        float4 v;
        v.x = dot[0];  v.y = dot[1];  v.z = dot[2];  v.w = dot[3];
        ((float4*)(feat_mat + i * NSRC + j0))[0] = v;
        v.x = dot[4];  v.y = dot[5];  v.z = dot[6];  v.w = dot[7];
        ((float4*)(feat_mat + i * NSRC + j0))[1] = v;
        v.x = dot[8];  v.y = dot[9];  v.z = dot[10]; v.w = dot[11];
        ((float4*)(feat_mat + i * NSRC + j0))[2] = v;
        v.x = dot[12]; v.y = dot[13]; v.z = dot[14]; v.w = dot[15];
        ((float4*)(feat_mat + i * NSRC + j0))[3] = v;

        float bv = -2.f; int bi = 0;
#pragma unroll
        for (int m = 0; m < 16; ++m) {
            const int j = j0 + m;
            // column argmax: packed (orderkey, 127-i), fire-and-forget
            const unsigned int b   = __float_as_uint(dot[m]);
            const unsigned int key = (b & 0x80000000u) ? ~b : (b | 0x80000000u);
            const unsigned long long packed =
                ((unsigned long long)key << 32) | (unsigned int)(127 - i);
            atomicMax(&colmax[j], packed);
            // row argmax: ascending j + strict > == first occurrence
            if (dot[m] > bv) { bv = dot[m]; bi = j; }
        }
        wmv[w] = bv; wmi[w] = bi;
    }
    __syncthreads();
    if (t == 0) {
        float fv = -2.f; int fi = 0;
        for (int ww = 0; ww < 8; ++ww)          // ascending wave == ascending j
            if (wmv[ww] > fv) { fv = wmv[ww]; fi = wmi[ww]; }
        rowF[i] = fv; rowFi[i] = fi;
    }
}

// ---------------------------------------------------------------------------
// K2 (1 x 1024): dist row/col argmax (LDS points, ONE shared d(i,j)
// expression -> bitwise-identical row vs col), feat argmax from rowF/colmax,
// gathers, stable ranks -> geo[512].
// ---------------------------------------------------------------------------
__global__ __launch_bounds__(1024) void geo_kernel(
    const float* __restrict__ pts_ws,
    const float* __restrict__ feat_mat,
    const float* __restrict__ rowF, const int* __restrict__ rowFi,
    const unsigned long long* __restrict__ colmax,
    float* __restrict__ geo_out)
{
    __shared__ float px[256], py[256], pz[256], nsq[256];
    __shared__ float pvD[1024]; __shared__ int piD[1024];
    __shared__ float min_dist[256];   __shared__ int match_idx[256];
    __shared__ float match_feat[256]; __shared__ int feat_idx[256];
    __shared__ float feat_score[256], match_dist[256];
    __shared__ int prD[1024]; __shared__ int prF[1024];

    const int t = threadIdx.x;
    if (t < 256) {
        px[t]  = pts_ws[t];
        py[t]  = pts_ws[256 + t];
        pz[t]  = pts_ws[512 + t];
        nsq[t] = pts_ws[768 + t];
    }
    __syncthreads();

    // ---- P2: chunked dist scans (4 chunks of 32) ----
    {
        const int rc = t & 255, q = t >> 8;
        float bdv = -1.f; int bdi = 0;
        if (rc < 128) {
            const int i = rc;
            for (int m = 0; m < 32; ++m) {
                const int j = q * 32 + m;
                float d = nsq[i] + nsq[128 + j]
                        - 2.0f * (px[i] * px[128 + j] + py[i] * py[128 + j] + pz[i] * pz[128 + j]);
                d = fmaxf(d, 0.f);
                const float v = expf(-d);
                if (v > bdv) { bdv = v; bdi = j; }
            }
        } else {
            const int j = rc - 128;
            for (int m = 0; m < 32; ++m) {
                const int i = q * 32 + m;
                float d = nsq[i] + nsq[128 + j]
                        - 2.0f * (px[i] * px[128 + j] + py[i] * py[128 + j] + pz[i] * pz[128 + j]);
                d = fmaxf(d, 0.f);
                const float v = expf(-d);
                if (v > bdv) { bdv = v; bdi = i; }
            }
        }
        pvD[q * 256 + rc] = bdv; piD[q * 256 + rc] = bdi;
    }
    __syncthreads();

    // ---- P3: combine dist chunks (ascending q + strict > == first occ);
    //          feat argmax from precomputed rowF / colmax ----
    if (t < 256) {
        float bv = -1.f; int bi = 0;
        for (int q = 0; q < 4; ++q) {
            const float v = pvD[q * 256 + t];
            if (v > bv) { bv = v; bi = piD[q * 256 + t]; }
        }
        min_dist[t] = bv; match_idx[t] = bi;
        if (t < 128) {
            match_feat[t] = rowF[t]; feat_idx[t] = rowFi[t];
        } else {
            const unsigned long long p = colmax[t - 128];
            const unsigned int key = (unsigned int)(p >> 32);
            const unsigned int fb  = (key & 0x80000000u) ? (key & 0x7FFFFFFFu) : ~key;
            match_feat[t] = __uint_as_float(fb);
            feat_idx[t]   = 127 - (int)(p & 0xFFFFFFFFu);
        }
    }
    __syncthreads();

    // ---- P4: gathers ----
    if (t < 256) {
        if (t < NREF) {
            const int i = t;
            feat_score[t] = feat_mat[i * NSRC + match_idx[t]];
            const int j = feat_idx[t];
            float d = nsq[i] + nsq[128 + j]
                    - 2.0f * (px[i] * px[128 + j] + py[i] * py[128 + j] + pz[i] * pz[128 + j]);
            d = fmaxf(d, 0.f);
            match_dist[t] = expf(-d);
        } else {
            const int j = t - 128;
            feat_score[t] = feat_mat[match_idx[t] * NSRC + j];
            const int i = feat_idx[t];
            float d = nsq[i] + nsq[128 + j]
                    - 2.0f * (px[i] * px[128 + j] + py[i] * py[128 + j] + pz[i] * pz[128 + j]);
            d = fmaxf(d, 0.f);
            match_dist[t] = expf(-d);
        }
    }
    __syncthreads();

    // ---- P5: stable descending ranks (== jnp.argsort(-v)), chunked 4x64 ----
    {
        const int e = t & 255, q = t >> 8;
        const float v  = min_dist[e];
        const float wv = match_feat[e];
        int r1 = 0, r2 = 0;
        for (int m = 0; m < 64; ++m) {
            const int j = q * 64 + m;
            const float u  = min_dist[j];
            r1 += (u > v) || (u == v && j < e);
            const float uf = match_feat[j];
            r2 += (uf > wv) || (uf == wv && j < e);
        }
        prD[q * 256 + e] = r1;
        prF[q * 256 + e] = r2;
    }
    __syncthreads();
    if (t < 256) {
        const int r  = prD[t] + prD[256 + t] + prD[512 + t] + prD[768 + t];
        geo_out[r] = min_dist[t] * feat_score[t];
        const int rf = prF[t] + prF[256 + t] + prF[512 + t] + prF[768 + t];
        geo_out[256 + rf] = match_dist[t] * match_feat[t];
    }
}

// ---------------------------------------------------------------------------
// K3: y1[c] = geo . W1[c,:] + b1[c]. 256 blocks x 64: W1's 512 KB streamed
// chip-wide (HBM-cold every iter: the 256 MB ws poison evicts caches).
// ---------------------------------------------------------------------------
__global__ __launch_bounds__(64) void mlp1_kernel(
    const float* __restrict__ geo,
    const float* __restrict__ W1, const float* __restrict__ b1,
    float* __restrict__ y1)
{
    const int c = blockIdx.x, l = threadIdx.x;
    const float4 ga = ((const float4*)geo)[l];
    const float4 gb = ((const float4*)geo)[64 + l];
    const float4* __restrict__ wrow = (const float4*)(W1 + c * 512);
    const float4 a = wrow[l];
    const float4 b = wrow[64 + l];
    float acc = a.x * ga.x + a.y * ga.y + a.z * ga.z + a.w * ga.w
              + b.x * gb.x + b.y * gb.y + b.z * gb.z + b.w * gb.w;
    acc += __shfl_down(acc, 32);
    acc += __shfl_down(acc, 16);
    acc += __shfl_down(acc, 8);
    acc += __shfl_down(acc, 4);
    acc += __shfl_down(acc, 2);
    acc += __shfl_down(acc, 1);
    if (l == 0) y1[c] = acc + b1[c];
}

// ---------------------------------------------------------------------------
// K4 (128 blocks x 64): h1 = relu(GN8(y1)*g1+bt1); y2[c] = h1.W2[c,:]+b2[c].
// LAST block (fence+atomic): GN8(y2) + output layer -> out[2].
// ---------------------------------------------------------------------------
__global__ __launch_bounds__(64) void mlp2_kernel(
    const float* __restrict__ y1,
    const float* __restrict__ g1, const float* __restrict__ bt1,
    const float* __restrict__ W2, const float* __restrict__ b2,
    const float* __restrict__ g2, const float* __restrict__ bt2,
    const float* __restrict__ W3, const float* __restrict__ b3,
    float* __restrict__ y2,
    float* __restrict__ out,
    int* __restrict__ counter)
{
    __shared__ __align__(16) float y1s[256];
    __shared__ float stats[16];
    __shared__ float y2s[128], h2s[128];
    __shared__ int is_last;
    const int c = blockIdx.x, l = threadIdx.x;
    ((float4*)y1s)[l] = ((const float4*)y1)[l];
    __syncthreads();
    if (l < 8) {
        float s = 0.f;
        for (int k = 0; k < 32; ++k) s += y1s[(l << 5) + k];
        const float mean = s * (1.0f / 32.0f);
        float q = 0.f;
        for (int k = 0; k < 32; ++k) { const float d = y1s[(l << 5) + k] - mean; q += d * d; }
        const float var = q * (1.0f / 32.0f);
        stats[l] = mean;
        stats[8 + l] = rsqrtf(var + EPS);
    }
    __syncthreads();
    {
        const float4 gg = ((const float4*)g1)[l];
        const float4 bb = ((const float4*)bt1)[l];
        const int g = l >> 3;
        const float mean = stats[g], inv = stats[8 + g];
        const float4 yv = ((const float4*)y1s)[l];
        float4 h;
        h.x = fmaxf((yv.x - mean) * inv * gg.x + bb.x, 0.f);
        h.y = fmaxf((yv.y - mean) * inv * gg.y + bb.y, 0.f);
        h.z = fmaxf((yv.z - mean) * inv * gg.z + bb.z, 0.f);
        h.w = fmaxf((yv.w - mean) * inv * gg.w + bb.w, 0.f);
        const float4 wv = ((const float4*)(W2 + c * 256))[l];
        float acc = wv.x * h.x + wv.y * h.y + wv.z * h.z + wv.w * h.w;
        acc += __shfl_down(acc, 32);
        acc += __shfl_down(acc, 16);
        acc += __shfl_down(acc, 8);
        acc += __shfl_down(acc, 4);
        acc += __shfl_down(acc, 2);
        acc += __shfl_down(acc, 1);
        if (l == 0) y2[c] = acc + b2[c];
    }

    // ---- arrive; last block runs GN2 + output layer (tiny post-fence) ----
    __threadfence();                       // release y2[c]
    if (l == 0) is_last = (atomicAdd(counter, 1) == 127);
    __syncthreads();
    if (!is_last) return;
    __threadfence();                       // acquire all y2

    y2s[l]      = y2[l];
    y2s[64 + l] = y2[64 + l];
    __syncthreads();
    for (int cc = l; cc < 128; cc += 64) {
        const int g = cc >> 4;
        float s = 0.f;
        for (int k = 0; k < 16; ++k) s += y2s[(g << 4) + k];
        const float mean = s * (1.0f / 16.0f);
        float q = 0.f;
        for (int k = 0; k < 16; ++k) { const float d = y2s[(g << 4) + k] - mean; q += d * d; }
        const float var = q * (1.0f / 16.0f);
        const float xn = (y2s[cc] - mean) * rsqrtf(var + EPS);
        h2s[cc] = fmaxf(xn * g2[cc] + bt2[cc], 0.f);
    }
    __syncthreads();
    for (int o = 0; o < 2; ++o) {
        float acc = W3[o * 128 + l] * h2s[l]
                  + W3[o * 128 + 64 + l] * h2s[64 + l];
        acc += __shfl_down(acc, 32);
        acc += __shfl_down(acc, 16);
        acc += __shfl_down(acc, 8);
        acc += __shfl_down(acc, 4);
        acc += __shfl_down(acc, 2);
        acc += __shfl_down(acc, 1);
        if (l == 0) out[o] = acc + b3[o];
    }
}

// ---------------------------------------------------------------------------
extern "C" void kernel_launch(void* const* d_in, const int* in_sizes, int n_in,
                              void* d_out, int out_size, void* d_ws, size_t ws_size,
                              hipStream_t stream)
{
    const float* points_c  = (const float*)d_in[0];
    const float* ref_feats = (const float*)d_in[1];
    const float* src_feats = (const float*)d_in[2];
    const float* trans     = (const float*)d_in[3];
    const float* W1  = (const float*)d_in[4];
    const float* b1  = (const float*)d_in[5];
    const float* g1  = (const float*)d_in[6];
    const float* bt1 = (const float*)d_in[7];
    const float* W2  = (const float*)d_in[8];
    const float* b2  = (const float*)d_in[9];
    const float* g2  = (const float*)d_in[10];
    const float* bt2 = (const float*)d_in[11];
    const float* W3  = (const float*)d_in[12];
    const float* b3  = (const float*)d_in[13];
    // d_in[14] = ref_length (int, == 128): fixed at compile time.

    // ws layout (float offsets):
    float* base     = (float*)d_ws;
    float* feat_mat = base;                   // [0, 16384)
    float* rowF     = base + 16384;           // [16384, 16512)
    int*   rowFi    = (int*)(base + 16512);   // [16512, 16640)
    float* pts_ws   = base + 16640;           // [16640, 17664)
    float* geo      = base + 17664;           // [17664, 18176)  16B aligned
    float* y1       = base + 18176;           // [18176, 18432)  16B aligned
    float* y2       = base + 18432;           // [18432, 18560)
    unsigned long long* colmax = (unsigned long long*)(base + 18560); // 128 u64, 8B aligned
    int*   counter  = (int*)(base + 18816);   // 1 int, right after colmax

    // zero colmax[128] + counter in one tiny memset (contiguous: 1028 B)
    hipMemsetAsync(colmax, 0, 128 * sizeof(unsigned long long) + sizeof(int), stream);

    feat_kernel<<<dim3(129), dim3(512), 0, stream>>>(
        ref_feats, src_feats, points_c, trans,
        feat_mat, rowF, rowFi, colmax, pts_ws);
    geo_kernel<<<dim3(1), dim3(1024), 0, stream>>>(
        pts_ws, feat_mat, rowF, rowFi, colmax, geo);
    mlp1_kernel<<<dim3(256), dim3(64), 0, stream>>>(geo, W1, b1, y1);
    mlp2_kernel<<<dim3(128), dim3(64), 0, stream>>>(
        y1, g1, bt1, W2, b2, g2, bt2, W3, b3, y2, (float*)d_out, counter);
}

// Round 7
// 106.383 us; speedup vs baseline: 1.2405x; 1.2405x over previous
//
#include <hip/hip_runtime.h>
#include <math.h>

// Problem constants (fixed by setup_inputs): N_ref=128, N_src=128, D=256.
#define NREF 128
#define NSRC 128
#define DIM  256
#define EPS  1e-5f

// ---------------------------------------------------------------------------
// K1 (128 blocks x 512): feat row i = ref_feats[i].src_feats[j] (all j),
// row-major store + per-row argmax (ascending j + strict > == jnp
// first-occurrence). 16 dwordx4 loads in flight, xor-butterfly reduce
// (validated bitwise vs np in R6).
// ---------------------------------------------------------------------------
__global__ __launch_bounds__(512) void feat_kernel(
    const float* __restrict__ ref_feats,
    const float* __restrict__ src_feats,
    float* __restrict__ feat_mat,
    float* __restrict__ rowF, int* __restrict__ rowFi)
{
    __shared__ __align__(16) float refrow[DIM];
    __shared__ float wmv[8];  __shared__ int wmi[8];

    const int t = threadIdx.x;
    const int w = t >> 6, l = t & 63;
    const int i = blockIdx.x;

    if (t < 64) ((float4*)refrow)[t] = ((const float4*)(ref_feats + i * DIM))[t];
    __syncthreads();

    const float4 r = ((const float4*)refrow)[l];

    float dot[16];
#pragma unroll
    for (int m = 0; m < 16; ++m) {
        const float4 a = ((const float4*)(src_feats + (w * 16 + m) * DIM))[l];
        dot[m] = a.x * r.x + a.y * r.y + a.z * r.z + a.w * r.w;
    }
#pragma unroll
    for (int m = 0; m < 16; ++m) {
        float s = dot[m];
        s += __shfl_xor(s, 32);
        s += __shfl_xor(s, 16);
        s += __shfl_xor(s, 8);
        s += __shfl_xor(s, 4);
        s += __shfl_xor(s, 2);
        s += __shfl_xor(s, 1);
        dot[m] = s;
    }

    if (l == 0) {
        const int j0 = w * 16;
        float4 v;
        v.x = dot[0];  v.y = dot[1];  v.z = dot[2];  v.w = dot[3];
        ((float4*)(feat_mat + i * NSRC + j0))[0] = v;
        v.x = dot[4];  v.y = dot[5];  v.z = dot[6];  v.w = dot[7];
        ((float4*)(feat_mat + i * NSRC + j0))[1] = v;
        v.x = dot[8];  v.y = dot[9];  v.z = dot[10]; v.w = dot[11];
        ((float4*)(feat_mat + i * NSRC + j0))[2] = v;
        v.x = dot[12]; v.y = dot[13]; v.z = dot[14]; v.w = dot[15];
        ((float4*)(feat_mat + i * NSRC + j0))[3] = v;

        float bv = -2.f; int bi = 0;
#pragma unroll
        for (int m = 0; m < 16; ++m)
            if (dot[m] > bv) { bv = dot[m]; bi = j0 + m; }   // ascending j, strict >
        wmv[w] = bv; wmi[w] = bi;
    }
    __syncthreads();
    if (t == 0) {
        float fv = -2.f; int fi = 0;
        for (int ww = 0; ww < 8; ++ww)          // ascending wave == ascending j
            if (wmv[ww] > fv) { fv = wmv[ww]; fi = wmi[ww]; }
        rowF[i] = fv; rowFi[i] = fi;
    }
}

// ---------------------------------------------------------------------------
// K2 (1 x 1024): point pipeline + dist row/col argmax (LDS points, ONE shared
// d(i,j) expression -> bitwise-identical row vs col) + feat COL argmax
// (coalesced, unrolled) + gathers + stable ranks -> geo[512].
// ---------------------------------------------------------------------------
__global__ __launch_bounds__(1024) void geo_kernel(
    const float* __restrict__ points_c,
    const float* __restrict__ trans,
    const float* __restrict__ feat_mat,
    const float* __restrict__ rowF, const int* __restrict__ rowFi,
    float* __restrict__ geo_out)
{
    __shared__ float px[256], py[256], pz[256], nsq[256];
    __shared__ float wred[16], red[4];
    __shared__ float pvD[1024]; __shared__ int piD[1024];
    __shared__ float pvF[512];  __shared__ int piF[512];
    __shared__ float min_dist[256];   __shared__ int match_idx[256];
    __shared__ float match_feat[256]; __shared__ int feat_idx[256];
    __shared__ float feat_score[256], match_dist[256];
    __shared__ int prD[1024]; __shared__ int prF[1024];

    const int t    = threadIdx.x;
    const int wave = t >> 6;
    const int lane = t & 63;

    // ---- P0: load points, transform src half ----
    float x = 0.f, y = 0.f, z = 0.f;
    if (t < 256) {
        x = points_c[3 * t + 0];
        y = points_c[3 * t + 1];
        z = points_c[3 * t + 2];
        if (t >= NREF) {
            float nx = trans[0] * x + trans[1] * y + trans[2]  * z + trans[3];
            float ny = trans[4] * x + trans[5] * y + trans[6]  * z + trans[7];
            float nz = trans[8] * x + trans[9] * y + trans[10] * z + trans[11];
            x = nx; y = ny; z = nz;
        }
        float sx = x, sy = y, sz = z;
        for (int off = 32; off >= 1; off >>= 1) {
            sx += __shfl_down(sx, off);
            sy += __shfl_down(sy, off);
            sz += __shfl_down(sz, off);
        }
        if (lane == 0) { wred[wave] = sx; wred[4 + wave] = sy; wred[8 + wave] = sz; }
    }
    __syncthreads();
    if (t == 0) {
        red[0] = (wred[0] + wred[1] + wred[2] + wred[3]) * (1.0f / 256.0f);
        red[1] = (wred[4] + wred[5] + wred[6] + wred[7]) * (1.0f / 256.0f);
        red[2] = (wred[8] + wred[9] + wred[10] + wred[11]) * (1.0f / 256.0f);
    }
    __syncthreads();

    // ---- P1: center, max-norm, normalize ----
    if (t < 256) {
        x -= red[0]; y -= red[1]; z -= red[2];
        float n = x * x + y * y + z * z;
        float mx = n;
        for (int off = 32; off >= 1; off >>= 1)
            mx = fmaxf(mx, __shfl_down(mx, off));
        if (lane == 0) wred[wave] = mx;
    }
    __syncthreads();
    if (t == 0)
        red[3] = 1.0f / sqrtf(fmaxf(fmaxf(wred[0], wred[1]), fmaxf(wred[2], wred[3])));
    __syncthreads();
    if (t < 256) {
        const float inv = red[3];
        x *= inv; y *= inv; z *= inv;
        px[t] = x; py[t] = y; pz[t] = z;
        nsq[t] = x * x + y * y + z * z;
    }
    __syncthreads();

    // ---- P2: chunked scans (4 chunks of 32). Col branch also scans feat
    // column j with coalesced, unroll-hoisted loads. ----
    {
        const int rc = t & 255, q = t >> 8;
        if (rc < 128) {
            const int i = rc;
            float bdv = -1.f; int bdi = 0;
#pragma unroll
            for (int m = 0; m < 32; ++m) {
                const int j = q * 32 + m;
                float d = nsq[i] + nsq[128 + j]
                        - 2.0f * (px[i] * px[128 + j] + py[i] * py[128 + j] + pz[i] * pz[128 + j]);
                d = fmaxf(d, 0.f);
                const float v = expf(-d);
                if (v > bdv) { bdv = v; bdi = j; }
            }
            pvD[q * 256 + rc] = bdv; piD[q * 256 + rc] = bdi;
        } else {
            const int j = rc - 128;
            // hoist the 32 feat-column loads (coalesced across lanes)
            float f[32];
#pragma unroll
            for (int m = 0; m < 32; ++m)
                f[m] = feat_mat[(q * 32 + m) * NSRC + j];
            float bdv = -1.f; int bdi = 0;
            float bfv = -2.f; int bfi = 0;
#pragma unroll
            for (int m = 0; m < 32; ++m) {
                const int i = q * 32 + m;
                float d = nsq[i] + nsq[128 + j]
                        - 2.0f * (px[i] * px[128 + j] + py[i] * py[128 + j] + pz[i] * pz[128 + j]);
                d = fmaxf(d, 0.f);
                const float v = expf(-d);
                if (v > bdv) { bdv = v; bdi = i; }
                if (f[m] > bfv) { bfv = f[m]; bfi = i; }
            }
            pvD[q * 256 + rc] = bdv; piD[q * 256 + rc] = bdi;
            pvF[q * 128 + j]  = bfv; piF[q * 128 + j]  = bfi;
        }
    }
    __syncthreads();

    // ---- P3: combine chunks (ascending q + strict > == first occurrence);
    //          feat row argmax from rowF/rowFi ----
    if (t < 256) {
        float bv = -1.f; int bi = 0;
        for (int q = 0; q < 4; ++q) {
            const float v = pvD[q * 256 + t];
            if (v > bv) { bv = v; bi = piD[q * 256 + t]; }
        }
        min_dist[t] = bv; match_idx[t] = bi;
        if (t < 128) {
            match_feat[t] = rowF[t]; feat_idx[t] = rowFi[t];
        } else {
            const int j = t - 128;
            float fv = -2.f; int fi = 0;
            for (int q = 0; q < 4; ++q) {
                const float v = pvF[q * 128 + j];
                if (v > fv) { fv = v; fi = piF[q * 128 + j]; }
            }
            match_feat[t] = fv; feat_idx[t] = fi;
        }
    }
    __syncthreads();

    // ---- P4: gathers ----
    if (t < 256) {
        if (t < NREF) {
            const int i = t;
            feat_score[t] = feat_mat[i * NSRC + match_idx[t]];
            const int j = feat_idx[t];
            float d = nsq[i] + nsq[128 + j]
                    - 2.0f * (px[i] * px[128 + j] + py[i] * py[128 + j] + pz[i] * pz[128 + j]);
            d = fmaxf(d, 0.f);
            match_dist[t] = expf(-d);
        } else {
            const int j = t - 128;
            feat_score[t] = feat_mat[match_idx[t] * NSRC + j];
            const int i = feat_idx[t];
            float d = nsq[i] + nsq[128 + j]
                    - 2.0f * (px[i] * px[128 + j] + py[i] * py[128 + j] + pz[i] * pz[128 + j]);
            d = fmaxf(d, 0.f);
            match_dist[t] = expf(-d);
        }
    }
    __syncthreads();

    // ---- P5: stable descending ranks (== jnp.argsort(-v)), chunked 4x64 ----
    {
        const int e = t & 255, q = t >> 8;
        const float v  = min_dist[e];
        const float wv = match_feat[e];
        int r1 = 0, r2 = 0;
        for (int m = 0; m < 64; ++m) {
            const int j = q * 64 + m;
            const float u  = min_dist[j];
            r1 += (u > v) || (u == v && j < e);
            const float uf = match_feat[j];
            r2 += (uf > wv) || (uf == wv && j < e);
        }
        prD[q * 256 + e] = r1;
        prF[q * 256 + e] = r2;
    }
    __syncthreads();
    if (t < 256) {
        const int r  = prD[t] + prD[256 + t] + prD[512 + t] + prD[768 + t];
        geo_out[r] = min_dist[t] * feat_score[t];
        const int rf = prF[t] + prF[256 + t] + prF[512 + t] + prF[768 + t];
        geo_out[256 + rf] = match_dist[t] * match_feat[t];
    }
}

// ---------------------------------------------------------------------------
// K3: y1[c] = geo . W1[c,:] + b1[c]. 256 blocks x 64: W1's 512 KB streamed
// chip-wide (HBM-cold every iter: the 256 MB ws poison evicts caches).
// ---------------------------------------------------------------------------
__global__ __launch_bounds__(64) void mlp1_kernel(
    const float* __restrict__ geo,
    const float* __restrict__ W1, const float* __restrict__ b1,
    float* __restrict__ y1)
{
    const int c = blockIdx.x, l = threadIdx.x;
    const float4 ga = ((const float4*)geo)[l];
    const float4 gb = ((const float4*)geo)[64 + l];
    const float4* __restrict__ wrow = (const float4*)(W1 + c * 512);
    const float4 a = wrow[l];
    const float4 b = wrow[64 + l];
    float acc = a.x * ga.x + a.y * ga.y + a.z * ga.z + a.w * ga.w
              + b.x * gb.x + b.y * gb.y + b.z * gb.z + b.w * gb.w;
    acc += __shfl_down(acc, 32);
    acc += __shfl_down(acc, 16);
    acc += __shfl_down(acc, 8);
    acc += __shfl_down(acc, 4);
    acc += __shfl_down(acc, 2);
    acc += __shfl_down(acc, 1);
    if (l == 0) y1[c] = acc + b1[c];
}

// ---------------------------------------------------------------------------
// K4 (128 blocks x 64): h1 = relu(GN8(y1)*g1+bt1); y2[c] = h1.W2[c,:]+b2[c].
// No fences, no atomics — kernel boundary is the (cheap) coherence point.
// ---------------------------------------------------------------------------
__global__ __launch_bounds__(64) void mlp2_kernel(
    const float* __restrict__ y1,
    const float* __restrict__ g1, const float* __restrict__ bt1,
    const float* __restrict__ W2, const float* __restrict__ b2,
    float* __restrict__ y2)
{
    __shared__ __align__(16) float y1s[256];
    __shared__ float stats[16];
    const int c = blockIdx.x, l = threadIdx.x;
    ((float4*)y1s)[l] = ((const float4*)y1)[l];
    __syncthreads();
    if (l < 8) {
        float s = 0.f;
        for (int k = 0; k < 32; ++k) s += y1s[(l << 5) + k];
        const float mean = s * (1.0f / 32.0f);
        float q = 0.f;
        for (int k = 0; k < 32; ++k) { const float d = y1s[(l << 5) + k] - mean; q += d * d; }
        const float var = q * (1.0f / 32.0f);
        stats[l] = mean;
        stats[8 + l] = rsqrtf(var + EPS);
    }
    __syncthreads();
    const float4 gg = ((const float4*)g1)[l];
    const float4 bb = ((const float4*)bt1)[l];
    const int g = l >> 3;
    const float mean = stats[g], inv = stats[8 + g];
    const float4 yv = ((const float4*)y1s)[l];
    float4 h;
    h.x = fmaxf((yv.x - mean) * inv * gg.x + bb.x, 0.f);
    h.y = fmaxf((yv.y - mean) * inv * gg.y + bb.y, 0.f);
    h.z = fmaxf((yv.z - mean) * inv * gg.z + bb.z, 0.f);
    h.w = fmaxf((yv.w - mean) * inv * gg.w + bb.w, 0.f);
    const float4 wv = ((const float4*)(W2 + c * 256))[l];
    float acc = wv.x * h.x + wv.y * h.y + wv.z * h.z + wv.w * h.w;
    acc += __shfl_down(acc, 32);
    acc += __shfl_down(acc, 16);
    acc += __shfl_down(acc, 8);
    acc += __shfl_down(acc, 4);
    acc += __shfl_down(acc, 2);
    acc += __shfl_down(acc, 1);
    if (l == 0) y2[c] = acc + b2[c];
}

// ---------------------------------------------------------------------------
// K5: h2 = relu(GN8(y2)*g2+bt2); out = h2 @ W3.T + b3. 1 x 128.
// ---------------------------------------------------------------------------
__global__ __launch_bounds__(128) void final_kernel(
    const float* __restrict__ y2,
    const float* __restrict__ g2, const float* __restrict__ bt2,
    const float* __restrict__ W3, const float* __restrict__ b3,
    float* __restrict__ out)
{
    __shared__ float y2s[128], h2[128];
    const int t = threadIdx.x;
    y2s[t] = y2[t];
    __syncthreads();
    {
        const int g = t >> 4;
        float s = 0.f;
        for (int k = 0; k < 16; ++k) s += y2s[(g << 4) + k];
        const float mean = s * (1.0f / 16.0f);
        float q = 0.f;
        for (int k = 0; k < 16; ++k) { const float d = y2s[(g << 4) + k] - mean; q += d * d; }
        const float var = q * (1.0f / 16.0f);
        const float xn = (y2s[t] - mean) * rsqrtf(var + EPS);
        h2[t] = fmaxf(xn * g2[t] + bt2[t], 0.f);
    }
    __syncthreads();
    const int wave = t >> 6, lane = t & 63;
    float acc = W3[wave * 128 + lane] * h2[lane]
              + W3[wave * 128 + 64 + lane] * h2[64 + lane];
    acc += __shfl_down(acc, 32);
    acc += __shfl_down(acc, 16);
    acc += __shfl_down(acc, 8);
    acc += __shfl_down(acc, 4);
    acc += __shfl_down(acc, 2);
    acc += __shfl_down(acc, 1);
    if (lane == 0) out[wave] = acc + b3[wave];
}

// ---------------------------------------------------------------------------
extern "C" void kernel_launch(void* const* d_in, const int* in_sizes, int n_in,
                              void* d_out, int out_size, void* d_ws, size_t ws_size,
                              hipStream_t stream)
{
    const float* points_c  = (const float*)d_in[0];
    const float* ref_feats = (const float*)d_in[1];
    const float* src_feats = (const float*)d_in[2];
    const float* trans     = (const float*)d_in[3];
    const float* W1  = (const float*)d_in[4];
    const float* b1  = (const float*)d_in[5];
    const float* g1  = (const float*)d_in[6];
    const float* bt1 = (const float*)d_in[7];
    const float* W2  = (const float*)d_in[8];
    const float* b2  = (const float*)d_in[9];
    const float* g2  = (const float*)d_in[10];
    const float* bt2 = (const float*)d_in[11];
    const float* W3  = (const float*)d_in[12];
    const float* b3  = (const float*)d_in[13];
    // d_in[14] = ref_length (int, == 128): fixed at compile time.

    // ws layout (float offsets):
    float* base     = (float*)d_ws;
    float* feat_mat = base;                   // [0, 16384)
    float* rowF     = base + 16384;           // [16384, 16512)
    int*   rowFi    = (int*)(base + 16512);   // [16512, 16640)
    float* geo      = base + 16640;           // [16640, 17152)  16B aligned
    float* y1       = base + 17152;           // [17152, 17408)  16B aligned
    float* y2       = base + 17408;           // [17408, 17536)

    feat_kernel<<<dim3(128), dim3(512), 0, stream>>>(
        ref_feats, src_feats, feat_mat, rowF, rowFi);
    geo_kernel<<<dim3(1), dim3(1024), 0, stream>>>(
        points_c, trans, feat_mat, rowF, rowFi, geo);
    mlp1_kernel<<<dim3(256), dim3(64), 0, stream>>>(geo, W1, b1, y1);
    mlp2_kernel<<<dim3(128), dim3(64), 0, stream>>>(y1, g1, bt1, W2, b2, y2);
    final_kernel<<<dim3(1), dim3(128), 0, stream>>>(y2, g2, bt2, W3, b3, (float*)d_out);
}